// Round 4
// baseline (187.807 us; speedup 1.0000x reference)
//
#include <hip/hip_runtime.h>
#include <math.h>

#define INF_ 100000.0f
constexpr int B_ = 64, W_ = 16, T_ = 64, U_ = 128, S_ = 20, N_ = 8;

typedef unsigned short ushort_t;
typedef __attribute__((ext_vector_type(8))) short bf16x8;
typedef __attribute__((ext_vector_type(4))) float floatx4;

static __device__ __forceinline__ unsigned short f2bf(float x) {
    unsigned int u = __float_as_uint(x);
    return (unsigned short)((u + 0x7fff + ((u >> 16) & 1)) >> 16);  // RNE
}
static __device__ __forceinline__ float bf2f(unsigned short s) {
    return __uint_as_float(((unsigned int)s) << 16);
}

// ---------------------------------------------------------------------------
// K_pre: everything that depends only on raw inputs.
//   blocks 0..63   : Gt[b][xn][u]   = sum_v qstat[b][xn][v] * weight[u][v]
//   blocks 64..127 : qs1T[b][j][xn] = sum_v qstat[b][xn][v] * W1[128+v][j]
//   blocks 128..143: w1topT[j][u] = W1[u][j]       (bf16)
//   blocks 144..159: w2T[m][j]    = W2[j][m]       (bf16)
//   block  160     : c_bf [32][128], rows >=20 zero
// ---------------------------------------------------------------------------
__global__ __launch_bounds__(256) void k_pre(
    const float* __restrict__ q_status, const float* __restrict__ weight,
    const float* __restrict__ W1, const float* __restrict__ W2,
    const float* __restrict__ c,
    ushort_t* __restrict__ w1topT, ushort_t* __restrict__ w2T,
    ushort_t* __restrict__ c_bf,
    ushort_t* __restrict__ Gt_bf, ushort_t* __restrict__ qs1T_bf)
{
    __shared__ __align__(16) ushort_t sw[128 * 136];
    __shared__ __align__(16) ushort_t sq[128 * 136];
    const int tid = threadIdx.x, bx = blockIdx.x;

    if (bx < 64) {
        const int b = bx;
        const float* qb = q_status + (size_t)b * 16384;
        for (int i = tid * 4; i < 16384; i += 1024) {
            int r = i >> 7, v = i & 127;
            float4 wv = *(const float4*)&weight[i];
            *(ushort4*)&sw[r * 136 + v] =
                (ushort4){f2bf(wv.x), f2bf(wv.y), f2bf(wv.z), f2bf(wv.w)};
            float4 qv = *(const float4*)&qb[i];
            *(ushort4*)&sq[r * 136 + v] =
                (ushort4){f2bf(qv.x), f2bf(qv.y), f2bf(qv.z), f2bf(qv.w)};
        }
        __syncthreads();
        const int wave = tid >> 6, lane = tid & 63, m16 = lane & 15, q = lane >> 4;
        ushort_t* Gb = Gt_bf + (size_t)b * 16384;
#pragma unroll
        for (int ci = 0; ci < 16; ++ci) {
            int tile = wave * 16 + ci;
            int mt = tile >> 3, jt = tile & 7;      // mt: xn-tile, jt: u-tile
            floatx4 acc = {0.f, 0.f, 0.f, 0.f};
#pragma unroll
            for (int kt = 0; kt < 4; ++kt) {
                bf16x8 a = *(const bf16x8*)&sq[(mt * 16 + m16) * 136 + kt * 32 + q * 8];
                bf16x8 w = *(const bf16x8*)&sw[(jt * 16 + m16) * 136 + kt * 32 + q * 8];
                acc = __builtin_amdgcn_mfma_f32_16x16x32_bf16(a, w, acc, 0, 0, 0);
            }
#pragma unroll
            for (int reg = 0; reg < 4; ++reg)
                Gb[(mt * 16 + q * 4 + reg) * 128 + jt * 16 + m16] = f2bf(acc[reg]);
        }
        return;
    }
    if (bx < 128) {
        const int b = bx - 64;
        const float* qb = q_status + (size_t)b * 16384;
        for (int i = tid * 4; i < 16384; i += 1024) {
            int r = i >> 7, v = i & 127;
            float4 qv = *(const float4*)&qb[i];
            *(ushort4*)&sq[r * 136 + v] =
                (ushort4){f2bf(qv.x), f2bf(qv.y), f2bf(qv.z), f2bf(qv.w)};
            // sw[j][v] = W1[(128+v)*128 + j] ; i-consec -> j consec (coalesced)
            int v2 = i >> 7, j = i & 127;
            float4 wv = *(const float4*)&W1[(128 + v2) * 128 + j];
            sw[(j + 0) * 136 + v2] = f2bf(wv.x);
            sw[(j + 1) * 136 + v2] = f2bf(wv.y);
            sw[(j + 2) * 136 + v2] = f2bf(wv.z);
            sw[(j + 3) * 136 + v2] = f2bf(wv.w);
        }
        __syncthreads();
        const int wave = tid >> 6, lane = tid & 63, m16 = lane & 15, q = lane >> 4;
        ushort_t* Qb = qs1T_bf + (size_t)b * 16384;
#pragma unroll
        for (int ci = 0; ci < 16; ++ci) {
            int tile = wave * 16 + ci;
            int mt = tile >> 3, jt = tile & 7;      // mt: xn-tile, jt: j-tile
            floatx4 acc = {0.f, 0.f, 0.f, 0.f};
#pragma unroll
            for (int kt = 0; kt < 4; ++kt) {
                bf16x8 a = *(const bf16x8*)&sq[(mt * 16 + m16) * 136 + kt * 32 + q * 8];
                bf16x8 w = *(const bf16x8*)&sw[(jt * 16 + m16) * 136 + kt * 32 + q * 8];
                acc = __builtin_amdgcn_mfma_f32_16x16x32_bf16(a, w, acc, 0, 0, 0);
            }
            // D: col=m16 <-> j, row=q*4+reg <-> xn ; store [j][xn]
            ushort4 o = {f2bf(acc[0]), f2bf(acc[1]), f2bf(acc[2]), f2bf(acc[3])};
            *(ushort4*)&Qb[(jt * 16 + m16) * 128 + mt * 16 + q * 4] = o;
        }
        return;
    }
    if (bx < 144) {
        int g = (bx - 128) * 1024 + tid * 4;
        int j = g >> 7, k = g & 127;
        *(ushort4*)&w1topT[g] =
            (ushort4){f2bf(W1[k * 128 + j]), f2bf(W1[(k + 1) * 128 + j]),
                      f2bf(W1[(k + 2) * 128 + j]), f2bf(W1[(k + 3) * 128 + j])};
        return;
    }
    if (bx < 160) {
        int g = (bx - 144) * 1024 + tid * 4;
        int j = g >> 7, k = g & 127;
        *(ushort4*)&w2T[g] =
            (ushort4){f2bf(W2[k * 128 + j]), f2bf(W2[(k + 1) * 128 + j]),
                      f2bf(W2[(k + 2) * 128 + j]), f2bf(W2[(k + 3) * 128 + j])};
        return;
    }
    // bx == 160: c_bf
    for (int i = tid * 4; i < 4096; i += 1024) {
        int s = i >> 7;
        ushort4 o = {0, 0, 0, 0};
        if (s < 20) {
            float4 v = *(const float4*)&c[i];
            o = (ushort4){f2bf(v.x), f2bf(v.y), f2bf(v.z), f2bf(v.w)};
        }
        *(ushort4*)&c_bf[i] = o;
    }
}

// ---------------------------------------------------------------------------
// K_main: per bw, everything: attention -> q_slot (LDS) -> co & A -> softmax
// -> h1^T -> h1 -> h2 -> logits.  640 threads, LDS arena 78336 B (2 blk/CU).
// Region map (ushort offsets):
//   SH_H   @0      [64][136]   P1-P2
//   SH_HT  @8704   [128][72]   P1-P4
//   SC f32 @17920  [32][68]    P2-P3   (float off 8960)
//   QSLOT  @17920  [32][136]   P4-P5   (reuses SC slot)
//   P_     @22272  [32][72]    P1(zero)-P4
//   CO     @22272  [20][132]   P5-P6   (reuses P_ slot)
//   P2_    @24912  [20][132]   P6-P7
//   A f32  @27552  [20][132]   P5-P8   (float off 13776)
//   QS1T   @0      [128][136]  P5-P7   (reuses SH_H/SH_HT)
//   H1     @0      [160][136]  P8-P9
//   W2T    @21760  [128][136]  P8.5-P9
// ---------------------------------------------------------------------------
__global__ __launch_bounds__(640, 5) void k_main(
    const float* __restrict__ h,          // [B,W,64,128] fp32
    const ushort_t* __restrict__ c_bf,    // [32][128], rows>=20 zero
    const float* __restrict__ pos,        // [B,W,20,128] fp32
    const ushort_t* __restrict__ Gt_bf,   // [B][128 xn][128 u]
    const ushort_t* __restrict__ qs1T_bf, // [B][128 j][128 xn]
    const ushort_t* __restrict__ w1topT,  // [128 j][128 u]
    const float* __restrict__ b1,
    const ushort_t* __restrict__ w2T,     // [128 m][128 j]
    const float* __restrict__ b2,
    const float* __restrict__ W3,
    const float* __restrict__ b3,
    float* __restrict__ lg)               // [B*W][160]
{
    __shared__ __align__(16) ushort_t sh[39168];   // 78336 B

    const int bw = blockIdx.x, b = bw >> 4, tid = threadIdx.x;
    const int wave = tid >> 6, lane = tid & 63, m16 = lane & 15, q = lane >> 4;

    // ---- P1: stage h -> sh_h [t][u] + sh_hT [u][t]; zero P_ ----
    const float* hb = h + (size_t)bw * 8192;
    for (int i = tid * 4; i < 8192; i += 2560) {
        int t = i >> 7, u = i & 127;
        float4 v = *(const float4*)&hb[i];
        ushort4 o = {f2bf(v.x), f2bf(v.y), f2bf(v.z), f2bf(v.w)};
        *(ushort4*)&sh[t * 136 + u] = o;
        sh[8704 + (u + 0) * 72 + t] = o.x;
        sh[8704 + (u + 1) * 72 + t] = o.y;
        sh[8704 + (u + 2) * 72 + t] = o.z;
        sh[8704 + (u + 3) * 72 + t] = o.w;
    }
    for (int i = tid; i < 2304; i += 640) sh[22272 + i] = 0;   // P_ zero
    __syncthreads();

    // ---- P2: GEMM1 sc[s][t] = c @ h^T (8 waves, 1 tile each) ----
    {
        float* sc = (float*)sh + 8960;
        if (wave < 8) {
            int mt = wave >> 2, jt = wave & 3;
            floatx4 acc = {0.f, 0.f, 0.f, 0.f};
#pragma unroll
            for (int kt = 0; kt < 4; ++kt) {
                bf16x8 a = *(const bf16x8*)&c_bf[(mt * 16 + m16) * 128 + kt * 32 + q * 8];
                bf16x8 bb = *(const bf16x8*)&sh[(jt * 16 + m16) * 136 + kt * 32 + q * 8];
                acc = __builtin_amdgcn_mfma_f32_16x16x32_bf16(a, bb, acc, 0, 0, 0);
            }
#pragma unroll
            for (int reg = 0; reg < 4; ++reg)
                sc[(mt * 16 + q * 4 + reg) * 68 + jt * 16 + m16] = acc[reg];
        }
    }
    __syncthreads();

    // ---- P3: softmax over t -> P_ (bf16) ----
    {
        const float* sc = (const float*)sh + 8960;
        for (int s = wave; s < 20; s += 10) {
            float v = sc[s * 68 + lane];
            if (v == 0.0f) v = -INF_;
            float m = v;
            for (int d = 32; d; d >>= 1) m = fmaxf(m, __shfl_xor(m, d));
            float e = expf(v - m);
            float sum = e;
            for (int d = 32; d; d >>= 1) sum += __shfl_xor(sum, d);
            sh[22272 + s * 72 + lane] = f2bf(e / sum);
        }
    }
    __syncthreads();

    // ---- P4: GEMM2 q_slot = P @ h + pos -> QSLOT (LDS) ----
    if (wave < 8) {
        const size_t obase = (size_t)bw * 2560;
#pragma unroll
        for (int ci = 0; ci < 2; ++ci) {
            int cmb = wave * 2 + ci;
            int mt = cmb >> 3, jt = cmb & 7;
            floatx4 acc = {0.f, 0.f, 0.f, 0.f};
#pragma unroll
            for (int kt = 0; kt < 2; ++kt) {
                bf16x8 a = *(const bf16x8*)&sh[22272 + (mt * 16 + m16) * 72 + kt * 32 + q * 8];
                bf16x8 bb = *(const bf16x8*)&sh[8704 + (jt * 16 + m16) * 72 + kt * 32 + q * 8];
                acc = __builtin_amdgcn_mfma_f32_16x16x32_bf16(a, bb, acc, 0, 0, 0);
            }
            int u = jt * 16 + m16;
#pragma unroll
            for (int reg = 0; reg < 4; ++reg) {
                int row = mt * 16 + q * 4 + reg;
                if (row < 20)
                    sh[17920 + row * 136 + u] =
                        f2bf(acc[reg] + pos[obase + row * 128 + u]);
            }
        }
    }
    __syncthreads();

    // ---- P5: stage qs1T -> QS1T@0; co (16 tiles) + A (16 tiles) ----
    for (int i = tid * 4; i < 16384; i += 2560) {
        int r = i >> 7, k2 = i & 127;
        *(ushort4*)&sh[r * 136 + k2] = *(const ushort4*)&qs1T_bf[(size_t)b * 16384 + i];
    }
    {
        const bf16x8 zz = {0, 0, 0, 0, 0, 0, 0, 0};
        float* Af = (float*)sh + 13776;
        const ushort_t* Gb = Gt_bf + (size_t)b * 16384;
        for (int t = wave; t < 32; t += 10) {
            int isA = t >> 4, tt = t & 15;
            int mt = tt >> 3, jt = tt & 7;
            int arow = mt * 16 + m16;
            const ushort_t* Bsrc = isA ? w1topT : Gb;
            floatx4 acc = {0.f, 0.f, 0.f, 0.f};
#pragma unroll
            for (int kt = 0; kt < 4; ++kt) {
                bf16x8 a = (arow < 20)
                    ? *(const bf16x8*)&sh[17920 + arow * 136 + kt * 32 + q * 8] : zz;
                bf16x8 g = *(const bf16x8*)&Bsrc[(jt * 16 + m16) * 128 + kt * 32 + q * 8];
                acc = __builtin_amdgcn_mfma_f32_16x16x32_bf16(a, g, acc, 0, 0, 0);
            }
            int col = jt * 16 + m16;
            if (isA) {
                float bv = b1[col];
#pragma unroll
                for (int reg = 0; reg < 4; ++reg) {
                    int row = mt * 16 + q * 4 + reg;
                    if (row < 20) Af[row * 132 + col] = acc[reg] + bv;
                }
            } else {
#pragma unroll
                for (int reg = 0; reg < 4; ++reg) {
                    int row = mt * 16 + q * 4 + reg;
                    if (row < 20) sh[22272 + row * 132 + col] = f2bf(acc[reg]);
                }
            }
        }
    }
    __syncthreads();

    // ---- P6: softmax over x: CO -> P2_ ----
    {
        int sn = tid >> 2, xi = tid & 3;
        int s = sn >> 3, n = sn & 7;
        const ushort_t* crow = &sh[22272 + s * 132];
        float v[4];
        float m = -INFINITY;
#pragma unroll
        for (int j = 0; j < 4; ++j) {
            float t = bf2f(crow[(xi + 4 * j) * 8 + n]);
            if (t == 0.0f) t = -INF_;
            v[j] = t;
            m = fmaxf(m, t);
        }
        m = fmaxf(m, __shfl_xor(m, 1));
        m = fmaxf(m, __shfl_xor(m, 2));
        float sum = 0.f;
#pragma unroll
        for (int j = 0; j < 4; ++j) { v[j] = expf(v[j] - m); sum += v[j]; }
        sum += __shfl_xor(sum, 1);
        sum += __shfl_xor(sum, 2);
        float r = 1.0f / sum;
#pragma unroll
        for (int j = 0; j < 4; ++j)
            sh[24912 + s * 132 + (xi + 4 * j) * 8 + n] = f2bf(v[j] * r);
    }
    __syncthreads();

    const int n = m16 & 7;
    const int sIdx = wave * 2 + (m16 >> 3);
    const int rowS = wave * 16 + m16;

    // ---- P7: h1^T MFMA (QS1T x sparse p2) ----
    floatx4 gacc[8];
#pragma unroll
    for (int mt = 0; mt < 8; ++mt) gacc[mt] = (floatx4){0.f, 0.f, 0.f, 0.f};
#pragma unroll
    for (int kt = 0; kt < 4; ++kt) {
        short pv = (short)sh[24912 + sIdx * 132 + kt * 32 + q * 8 + n];
        bf16x8 pf = {0, 0, 0, 0, 0, 0, 0, 0};
        pf[0] = (n == 0) ? pv : (short)0;
        pf[1] = (n == 1) ? pv : (short)0;
        pf[2] = (n == 2) ? pv : (short)0;
        pf[3] = (n == 3) ? pv : (short)0;
        pf[4] = (n == 4) ? pv : (short)0;
        pf[5] = (n == 5) ? pv : (short)0;
        pf[6] = (n == 6) ? pv : (short)0;
        pf[7] = (n == 7) ? pv : (short)0;
#pragma unroll
        for (int mt = 0; mt < 8; ++mt) {
            bf16x8 af = *(const bf16x8*)&sh[(mt * 16 + m16) * 136 + kt * 32 + q * 8];
            gacc[mt] = __builtin_amdgcn_mfma_f32_16x16x32_bf16(af, pf, gacc[mt], 0, 0, 0);
        }
    }
    __syncthreads();   // QS1T/P2_ reads done

    // ---- P8: h1 = relu(gacc + A) -> H1@0 (A region disjoint from H1) ----
    {
        const float* Af = (const float*)sh + 13776 + sIdx * 132;
#pragma unroll
        for (int mt = 0; mt < 8; ++mt) {
            int u0 = mt * 16 + q * 4;
            float4 av = *(const float4*)&Af[u0];
            ushort4 o;
            o.x = f2bf(fmaxf(gacc[mt][0] + av.x, 0.f));
            o.y = f2bf(fmaxf(gacc[mt][1] + av.y, 0.f));
            o.z = f2bf(fmaxf(gacc[mt][2] + av.z, 0.f));
            o.w = f2bf(fmaxf(gacc[mt][3] + av.w, 0.f));
            *(ushort4*)&sh[rowS * 136 + u0] = o;
        }
    }
    __syncthreads();   // A reads done; W2T region now free

    // ---- P8.5: stage w2T -> @21760 ----
    for (int i = tid * 4; i < 16384; i += 2560) {
        int r = i >> 7, k2 = i & 127;
        *(ushort4*)&sh[21760 + r * 136 + k2] = *(const ushort4*)&w2T[i];
    }
    __syncthreads();

    // ---- P9: h2 GEMM + epilogue ----
    floatx4 acc[8];
#pragma unroll
    for (int jt = 0; jt < 8; ++jt) acc[jt] = (floatx4){0.f, 0.f, 0.f, 0.f};
#pragma unroll
    for (int kt = 0; kt < 4; ++kt) {
        const int k0 = kt * 32 + q * 8;
        bf16x8 af = *(const bf16x8*)&sh[rowS * 136 + k0];
#pragma unroll
        for (int jt = 0; jt < 8; ++jt) {
            bf16x8 bfr = *(const bf16x8*)&sh[21760 + (jt * 16 + m16) * 136 + k0];
            acc[jt] = __builtin_amdgcn_mfma_f32_16x16x32_bf16(af, bfr, acc[jt], 0, 0, 0);
        }
    }

    float b2v[8], w3v[8];
#pragma unroll
    for (int jt = 0; jt < 8; ++jt) {
        b2v[jt] = b2[jt * 16 + m16];
        w3v[jt] = W3[jt * 16 + m16];
    }
    const float b3v = b3[0];

#pragma unroll
    for (int reg = 0; reg < 4; ++reg) {
        float p = 0.f;
#pragma unroll
        for (int jt = 0; jt < 8; ++jt)
            p += fmaxf(acc[jt][reg] + b2v[jt], 0.f) * w3v[jt];
        p += __shfl_xor(p, 1);
        p += __shfl_xor(p, 2);
        p += __shfl_xor(p, 4);
        p += __shfl_xor(p, 8);
        if (m16 == 0)
            lg[(size_t)bw * 160 + wave * 16 + q * 4 + reg] = p + b3v;
    }
}

// ---------------------------------------------------------------------------
// K5: masked max over W, labels, scalar.
// ---------------------------------------------------------------------------
__global__ __launch_bounds__(256) void k5_final(
    const float* __restrict__ lg,
    const float* __restrict__ mask,
    float* __restrict__ out)
{
    int idx = blockIdx.x * 256 + threadIdx.x;
    const int SN = S_ * N_;
    if (idx < B_ * SN) {
        int b = idx / SN, sn = idx % SN;
        float m = -INFINITY;
        for (int w = 0; w < W_; ++w) {
            float v = lg[((size_t)b * W_ + w) * SN + sn] + mask[((size_t)b * W_ + w) * SN + sn];
            m = fmaxf(m, v);
        }
        out[idx] = (m > 0.f) ? 1.f : 0.f;
        out[B_ * SN + 1 + idx] = m;
    }
    if (idx == 0) out[B_ * SN] = (float)SN;
}

// ---------------------------------------------------------------------------
extern "C" void kernel_launch(void* const* d_in, const int* in_sizes, int n_in,
                              void* d_out, int out_size, void* d_ws, size_t ws_size,
                              hipStream_t stream) {
    const float* slot_utt_h = (const float*)d_in[0];
    const float* slot_candidate_c = (const float*)d_in[1];
    const float* position_encoding = (const float*)d_in[3];
    const float* q_status = (const float*)d_in[4];
    const float* mask = (const float*)d_in[5];
    const float* weight = (const float*)d_in[6];
    const float* W1 = (const float*)d_in[7];
    const float* b1 = (const float*)d_in[8];
    const float* W2 = (const float*)d_in[9];
    const float* b2 = (const float*)d_in[10];
    const float* W3 = (const float*)d_in[11];
    const float* b3 = (const float*)d_in[12];
    float* out = (float*)d_out;

    float* f = (float*)d_ws;
    float*    lg       = f + 0;                       //   163,840 f
    ushort_t* Gt_bf    = (ushort_t*)(f + 163840);     // 1,048,576 sh
    ushort_t* qs1T_bf  = (ushort_t*)(f + 688128);     // 1,048,576 sh
    ushort_t* w1topT   = (ushort_t*)(f + 1212416);    //    16,384 sh
    ushort_t* w2T      = (ushort_t*)(f + 1220608);    //    16,384 sh
    ushort_t* c_bf     = (ushort_t*)(f + 1228800);    //     4,096 sh

    k_pre<<<161, 256, 0, stream>>>(q_status, weight, W1, W2,
                                   slot_candidate_c,
                                   w1topT, w2T, c_bf, Gt_bf, qs1T_bf);
    k_main<<<1024, 640, 0, stream>>>(slot_utt_h, c_bf, position_encoding,
                                     Gt_bf, qs1T_bf, w1topT, b1, w2T,
                                     b2, W3, b3, lg);
    k5_final<<<(B_ * S_ * N_ + 255) / 256, 256, 0, stream>>>(lg, mask, out);
}

// Round 5
// 178.864 us; speedup vs baseline: 1.0500x; 1.0500x over previous
//
#include <hip/hip_runtime.h>
#include <math.h>

#define INF_ 100000.0f
constexpr int B_ = 64, W_ = 16, T_ = 64, U_ = 128, S_ = 20, N_ = 8;

typedef unsigned short ushort_t;
typedef __attribute__((ext_vector_type(8))) short bf16x8;
typedef __attribute__((ext_vector_type(4))) float floatx4;

static __device__ __forceinline__ unsigned short f2bf(float x) {
    unsigned int u = __float_as_uint(x);
    return (unsigned short)((u + 0x7fff + ((u >> 16) & 1)) >> 16);  // RNE
}
static __device__ __forceinline__ float bf2f(unsigned short s) {
    return __uint_as_float(((unsigned int)s) << 16);
}

// ---------------------------------------------------------------------------
// K_pre (verbatim, proven): input-only derived tensors.
//   blocks 0..63   : Gt[b][xn][u]   = sum_v qstat[b][xn][v] * weight[u][v]
//   blocks 64..127 : qs1T[b][j][xn] = sum_v qstat[b][xn][v] * W1[128+v][j]
//   blocks 128..143: w1topT[j][u] = W1[u][j]
//   blocks 144..159: w2T[j][k]    = W2[k][j]
//   block  160     : c_bf [32][128], rows >=20 zero
// ---------------------------------------------------------------------------
__global__ __launch_bounds__(256) void k_pre(
    const float* __restrict__ q_status, const float* __restrict__ weight,
    const float* __restrict__ W1, const float* __restrict__ W2,
    const float* __restrict__ c,
    ushort_t* __restrict__ w1topT, ushort_t* __restrict__ w2T,
    ushort_t* __restrict__ c_bf,
    ushort_t* __restrict__ Gt_bf, ushort_t* __restrict__ qs1T_bf)
{
    __shared__ __align__(16) ushort_t sw[128 * 136];
    __shared__ __align__(16) ushort_t sq[128 * 136];
    const int tid = threadIdx.x, bx = blockIdx.x;

    if (bx < 64) {
        const int b = bx;
        const float* qb = q_status + (size_t)b * 16384;
        for (int i = tid * 4; i < 16384; i += 1024) {
            int r = i >> 7, v = i & 127;
            float4 wv = *(const float4*)&weight[i];
            *(ushort4*)&sw[r * 136 + v] =
                (ushort4){f2bf(wv.x), f2bf(wv.y), f2bf(wv.z), f2bf(wv.w)};
            float4 qv = *(const float4*)&qb[i];
            *(ushort4*)&sq[r * 136 + v] =
                (ushort4){f2bf(qv.x), f2bf(qv.y), f2bf(qv.z), f2bf(qv.w)};
        }
        __syncthreads();
        const int wave = tid >> 6, lane = tid & 63, m16 = lane & 15, q = lane >> 4;
        ushort_t* Gb = Gt_bf + (size_t)b * 16384;
#pragma unroll
        for (int ci = 0; ci < 16; ++ci) {
            int tile = wave * 16 + ci;
            int mt = tile >> 3, jt = tile & 7;
            floatx4 acc = {0.f, 0.f, 0.f, 0.f};
#pragma unroll
            for (int kt = 0; kt < 4; ++kt) {
                bf16x8 a = *(const bf16x8*)&sq[(mt * 16 + m16) * 136 + kt * 32 + q * 8];
                bf16x8 w = *(const bf16x8*)&sw[(jt * 16 + m16) * 136 + kt * 32 + q * 8];
                acc = __builtin_amdgcn_mfma_f32_16x16x32_bf16(a, w, acc, 0, 0, 0);
            }
#pragma unroll
            for (int reg = 0; reg < 4; ++reg)
                Gb[(mt * 16 + q * 4 + reg) * 128 + jt * 16 + m16] = f2bf(acc[reg]);
        }
        return;
    }
    if (bx < 128) {
        const int b = bx - 64;
        const float* qb = q_status + (size_t)b * 16384;
        for (int i = tid * 4; i < 16384; i += 1024) {
            int r = i >> 7, v = i & 127;
            float4 qv = *(const float4*)&qb[i];
            *(ushort4*)&sq[r * 136 + v] =
                (ushort4){f2bf(qv.x), f2bf(qv.y), f2bf(qv.z), f2bf(qv.w)};
            int v2 = i >> 7, j = i & 127;
            float4 wv = *(const float4*)&W1[(128 + v2) * 128 + j];
            sw[(j + 0) * 136 + v2] = f2bf(wv.x);
            sw[(j + 1) * 136 + v2] = f2bf(wv.y);
            sw[(j + 2) * 136 + v2] = f2bf(wv.z);
            sw[(j + 3) * 136 + v2] = f2bf(wv.w);
        }
        __syncthreads();
        const int wave = tid >> 6, lane = tid & 63, m16 = lane & 15, q = lane >> 4;
        ushort_t* Qb = qs1T_bf + (size_t)b * 16384;
#pragma unroll
        for (int ci = 0; ci < 16; ++ci) {
            int tile = wave * 16 + ci;
            int mt = tile >> 3, jt = tile & 7;
            floatx4 acc = {0.f, 0.f, 0.f, 0.f};
#pragma unroll
            for (int kt = 0; kt < 4; ++kt) {
                bf16x8 a = *(const bf16x8*)&sq[(mt * 16 + m16) * 136 + kt * 32 + q * 8];
                bf16x8 w = *(const bf16x8*)&sw[(jt * 16 + m16) * 136 + kt * 32 + q * 8];
                acc = __builtin_amdgcn_mfma_f32_16x16x32_bf16(a, w, acc, 0, 0, 0);
            }
            ushort4 o = {f2bf(acc[0]), f2bf(acc[1]), f2bf(acc[2]), f2bf(acc[3])};
            *(ushort4*)&Qb[(jt * 16 + m16) * 128 + mt * 16 + q * 4] = o;
        }
        return;
    }
    if (bx < 144) {
        int g = (bx - 128) * 1024 + tid * 4;
        int j = g >> 7, k = g & 127;
        *(ushort4*)&w1topT[g] =
            (ushort4){f2bf(W1[k * 128 + j]), f2bf(W1[(k + 1) * 128 + j]),
                      f2bf(W1[(k + 2) * 128 + j]), f2bf(W1[(k + 3) * 128 + j])};
        return;
    }
    if (bx < 160) {
        int g = (bx - 144) * 1024 + tid * 4;
        int j = g >> 7, k = g & 127;
        *(ushort4*)&w2T[g] =
            (ushort4){f2bf(W2[k * 128 + j]), f2bf(W2[(k + 1) * 128 + j]),
                      f2bf(W2[(k + 2) * 128 + j]), f2bf(W2[(k + 3) * 128 + j])};
        return;
    }
    for (int i = tid * 4; i < 4096; i += 1024) {
        int s = i >> 7;
        ushort4 o = {0, 0, 0, 0};
        if (s < 20) {
            float4 v = *(const float4*)&c[i];
            o = (ushort4){f2bf(v.x), f2bf(v.y), f2bf(v.z), f2bf(v.w)};
        }
        *(ushort4*)&c_bf[i] = o;
    }
}

// ---------------------------------------------------------------------------
// kA: attention per bw. 256 thr, LDS 31744 B -> 5 blk/CU (20 waves).
// GEMM1 operands straight from global (c_bf L2-hot, h f32->bf16 inline);
// only hT staged in LDS (needed as GEMM2 B).  2 barriers.
// ---------------------------------------------------------------------------
__global__ __launch_bounds__(256) void kA(
    const float* __restrict__ h,        // [B*W][64][128] f32
    const ushort_t* __restrict__ c_bf,  // [32][128], rows>=20 zero
    const float* __restrict__ pos,      // [B*W][20][128] f32
    ushort_t* __restrict__ q_slot_bf)   // [20480][128]
{
    __shared__ __align__(16) ushort_t sh_hT[128 * 72];  // [u][t] 18432 B
    __shared__ __align__(16) float    sh_sc[32 * 68];   //  8704 B
    __shared__ __align__(16) ushort_t sh_P[32 * 72];    //  4608 B

    const int bw = blockIdx.x, tid = threadIdx.x;
    const int wave = tid >> 6, lane = tid & 63, m16 = lane & 15, q = lane >> 4;
    const float* hb = h + (size_t)bw * 8192;

    // P1: stage hT (scalar transposed writes) + zero P
    for (int i = tid * 4; i < 8192; i += 1024) {
        int t = i >> 7, u = i & 127;
        float4 v = *(const float4*)&hb[i];
        sh_hT[(u + 0) * 72 + t] = f2bf(v.x);
        sh_hT[(u + 1) * 72 + t] = f2bf(v.y);
        sh_hT[(u + 2) * 72 + t] = f2bf(v.z);
        sh_hT[(u + 3) * 72 + t] = f2bf(v.w);
    }
    for (int i = tid; i < 2304; i += 256) sh_P[i] = 0;

    // P2: sc = c @ h^T, A/B from global (no LDS dependence)
#pragma unroll
    for (int ci = 0; ci < 2; ++ci) {
        int cmb = wave * 2 + ci;                 // 0..7
        int mt = cmb >> 2, jt = cmb & 3;
        floatx4 acc = {0.f, 0.f, 0.f, 0.f};
#pragma unroll
        for (int kt = 0; kt < 4; ++kt) {
            bf16x8 a = *(const bf16x8*)&c_bf[(mt * 16 + m16) * 128 + kt * 32 + q * 8];
            const float* hp = &hb[(jt * 16 + m16) * 128 + kt * 32 + q * 8];
            float4 b0 = *(const float4*)&hp[0];
            float4 b1v = *(const float4*)&hp[4];
            bf16x8 bb;
            bb[0] = (short)f2bf(b0.x); bb[1] = (short)f2bf(b0.y);
            bb[2] = (short)f2bf(b0.z); bb[3] = (short)f2bf(b0.w);
            bb[4] = (short)f2bf(b1v.x); bb[5] = (short)f2bf(b1v.y);
            bb[6] = (short)f2bf(b1v.z); bb[7] = (short)f2bf(b1v.w);
            acc = __builtin_amdgcn_mfma_f32_16x16x32_bf16(a, bb, acc, 0, 0, 0);
        }
#pragma unroll
        for (int reg = 0; reg < 4; ++reg)
            sh_sc[(mt * 16 + q * 4 + reg) * 68 + jt * 16 + m16] = acc[reg];
    }
    __syncthreads();

    // P3: softmax over t
    for (int s = wave; s < 20; s += 4) {
        float v = sh_sc[s * 68 + lane];
        if (v == 0.0f) v = -INF_;
        float m = v;
        for (int d = 32; d; d >>= 1) m = fmaxf(m, __shfl_xor(m, d));
        float e = expf(v - m);
        float sum = e;
        for (int d = 32; d; d >>= 1) sum += __shfl_xor(sum, d);
        sh_P[s * 72 + lane] = f2bf(e / sum);
    }
    __syncthreads();

    // P4: q_slot = P@h + pos -> global bf16
    const size_t obase = (size_t)bw * 2560;
#pragma unroll
    for (int ci = 0; ci < 4; ++ci) {
        int cmb = wave * 4 + ci;                 // 0..15
        int mt = cmb >> 3, jt = cmb & 7;
        floatx4 acc = {0.f, 0.f, 0.f, 0.f};
#pragma unroll
        for (int kt = 0; kt < 2; ++kt) {
            bf16x8 a = *(const bf16x8*)&sh_P[(mt * 16 + m16) * 72 + kt * 32 + q * 8];
            bf16x8 b = *(const bf16x8*)&sh_hT[(jt * 16 + m16) * 72 + kt * 32 + q * 8];
            acc = __builtin_amdgcn_mfma_f32_16x16x32_bf16(a, b, acc, 0, 0, 0);
        }
        int u = jt * 16 + m16;
#pragma unroll
        for (int reg = 0; reg < 4; ++reg) {
            int row = mt * 16 + q * 4 + reg;
            if (row < 20)
                q_slot_bf[obase + row * 128 + u] =
                    f2bf(acc[reg] + pos[obase + row * 128 + u]);
        }
    }
}

// ---------------------------------------------------------------------------
// kB: dense batched GEMMs.  256 thr, LDS 34816 B -> 4 blk/CU.
//   blocks 0..319  : co[b][r][xn] = q_slot[b-rows] @ Gt[b]^T  (b=bx/5, rt=bx%5)
//   blocks 320..639: A = q_slot @ W1top + b1   (64 rows per block)
// ---------------------------------------------------------------------------
__global__ __launch_bounds__(256) void kB(
    const ushort_t* __restrict__ q_slot_bf,  // [20480][128]
    const ushort_t* __restrict__ Gt_bf,      // [B][128][128]
    const ushort_t* __restrict__ w1topT,     // [128][128]
    const float* __restrict__ b1,
    ushort_t* __restrict__ co_bf,            // [B][320][128]
    float* __restrict__ A)                   // [20480][128]
{
    __shared__ __align__(16) ushort_t shB[128 * 136];
    const int tid = threadIdx.x, bx = blockIdx.x;
    const int wave = tid >> 6, lane = tid & 63, m16 = lane & 15, q = lane >> 4;

    if (bx < 320) {
        const int b = bx / 5, rt = bx - b * 5;
        for (int i = tid * 4; i < 16384; i += 1024)
            *(ushort4*)&shB[(i >> 7) * 136 + (i & 127)] =
                *(const ushort4*)&Gt_bf[(size_t)b * 16384 + i];
        __syncthreads();

        const size_t rbase = (size_t)b * 320 + rt * 64 + wave * 16;
        floatx4 acc[8];
#pragma unroll
        for (int jt = 0; jt < 8; ++jt) acc[jt] = (floatx4){0.f, 0.f, 0.f, 0.f};
#pragma unroll
        for (int kt = 0; kt < 4; ++kt) {
            bf16x8 a = *(const bf16x8*)&q_slot_bf[(rbase + m16) * 128 + kt * 32 + q * 8];
#pragma unroll
            for (int jt = 0; jt < 8; ++jt) {
                bf16x8 g = *(const bf16x8*)&shB[(jt * 16 + m16) * 136 + kt * 32 + q * 8];
                acc[jt] = __builtin_amdgcn_mfma_f32_16x16x32_bf16(a, g, acc[jt], 0, 0, 0);
            }
        }
#pragma unroll
        for (int jt = 0; jt < 8; ++jt)
#pragma unroll
            for (int reg = 0; reg < 4; ++reg)
                co_bf[(rbase + q * 4 + reg) * 128 + jt * 16 + m16] = f2bf(acc[jt][reg]);
    } else {
        const int blk = bx - 320;                // 0..319, 64 rows each
        for (int i = tid * 4; i < 16384; i += 1024)
            *(ushort4*)&shB[(i >> 7) * 136 + (i & 127)] =
                *(const ushort4*)&w1topT[i];
        __syncthreads();

        const size_t rbase = (size_t)blk * 64 + wave * 16;
        floatx4 acc[8];
#pragma unroll
        for (int jt = 0; jt < 8; ++jt) acc[jt] = (floatx4){0.f, 0.f, 0.f, 0.f};
#pragma unroll
        for (int kt = 0; kt < 4; ++kt) {
            bf16x8 a = *(const bf16x8*)&q_slot_bf[(rbase + m16) * 128 + kt * 32 + q * 8];
#pragma unroll
            for (int jt = 0; jt < 8; ++jt) {
                bf16x8 g = *(const bf16x8*)&shB[(jt * 16 + m16) * 136 + kt * 32 + q * 8];
                acc[jt] = __builtin_amdgcn_mfma_f32_16x16x32_bf16(a, g, acc[jt], 0, 0, 0);
            }
        }
#pragma unroll
        for (int jt = 0; jt < 8; ++jt) {
            int col = jt * 16 + m16;
            float bv = b1[col];
#pragma unroll
            for (int reg = 0; reg < 4; ++reg)
                A[(rbase + q * 4 + reg) * 128 + col] = acc[jt][reg] + bv;
        }
    }
}

// ---------------------------------------------------------------------------
// kC: softmax(co) -> h1^T -> h1(reg) -> quad-shuffle -> h2 -> logits.
// 640 thr, LDS 74912 B (2 blk/CU) but ONE barrier and no H1 LDS round trip.
// h1^T D-layout: lane (m16,q) holds h1[u=mt*16+q*4+reg][sn=wave*16+m16].
// h2 A-frag needs h1[sn=wave*16+m16][u=kt*32+q*8+e]: same m16 -> only the
// u-dim moves across the 4 q-lanes of each m16 group (quad shuffles).
// ---------------------------------------------------------------------------
__global__ __launch_bounds__(640, 5) void kC(
    const ushort_t* __restrict__ co_bf,    // [B][320][128]
    const ushort_t* __restrict__ qs1T_bf,  // [B][128 u][128 xn]
    const float* __restrict__ A,           // [20480][128]
    const ushort_t* __restrict__ w2T,      // [128 j][128 k]
    const float* __restrict__ b2,
    const float* __restrict__ W3,
    const float* __restrict__ b3,
    float* __restrict__ lg)                // [B*W][160]
{
    __shared__ __align__(16) ushort_t shQ[128 * 136];  // qs1T  34816 B
    __shared__ __align__(16) ushort_t shW[128 * 136];  // w2T   34816 B
    __shared__ __align__(16) ushort_t shP[20 * 132];   // p2     5280 B

    const int bw = blockIdx.x, b = bw >> 4, tid = threadIdx.x;
    const int wave = tid >> 6, lane = tid & 63, m16 = lane & 15, q = lane >> 4;

    // stage qs1T[b] + w2T
    for (int i = tid * 4; i < 16384; i += 2560) {
        int r = i >> 7, k = i & 127;
        *(ushort4*)&shQ[r * 136 + k] = *(const ushort4*)&qs1T_bf[(size_t)b * 16384 + i];
        *(ushort4*)&shW[r * 136 + k] = *(const ushort4*)&w2T[i];
    }

    // softmax over x (co from global; 640 thr cover 160 sn x 4 xi)
    {
        int sn = tid >> 2, xi = tid & 3;
        int s = sn >> 3, n2 = sn & 7;
        const ushort_t* crow = co_bf + ((size_t)bw * 20 + s) * 128;
        float v[4];
        float m = -INFINITY;
#pragma unroll
        for (int j = 0; j < 4; ++j) {
            float t = bf2f(crow[(xi + 4 * j) * 8 + n2]);
            if (t == 0.0f) t = -INF_;
            v[j] = t;
            m = fmaxf(m, t);
        }
        m = fmaxf(m, __shfl_xor(m, 1));
        m = fmaxf(m, __shfl_xor(m, 2));
        float sum = 0.f;
#pragma unroll
        for (int j = 0; j < 4; ++j) { v[j] = expf(v[j] - m); sum += v[j]; }
        sum += __shfl_xor(sum, 1);
        sum += __shfl_xor(sum, 2);
        float r = 1.0f / sum;
#pragma unroll
        for (int j = 0; j < 4; ++j)
            shP[s * 132 + (xi + 4 * j) * 8 + n2] = f2bf(v[j] * r);
    }
    __syncthreads();   // the only barrier

    const int n = m16 & 7;
    const int sIdx = wave * 2 + (m16 >> 3);

    // h1^T MFMA: A-frags from LDS shQ, sparse-p2 B-frags
    floatx4 gacc[8];
#pragma unroll
    for (int mt = 0; mt < 8; ++mt) gacc[mt] = (floatx4){0.f, 0.f, 0.f, 0.f};
#pragma unroll
    for (int kt = 0; kt < 4; ++kt) {
        short pv = (short)shP[sIdx * 132 + kt * 32 + q * 8 + n];
        bf16x8 pf = {0, 0, 0, 0, 0, 0, 0, 0};
        pf[0] = (n == 0) ? pv : (short)0;
        pf[1] = (n == 1) ? pv : (short)0;
        pf[2] = (n == 2) ? pv : (short)0;
        pf[3] = (n == 3) ? pv : (short)0;
        pf[4] = (n == 4) ? pv : (short)0;
        pf[5] = (n == 5) ? pv : (short)0;
        pf[6] = (n == 6) ? pv : (short)0;
        pf[7] = (n == 7) ? pv : (short)0;
#pragma unroll
        for (int mt = 0; mt < 8; ++mt) {
            bf16x8 af = *(const bf16x8*)&shQ[(mt * 16 + m16) * 136 + kt * 32 + q * 8];
            gacc[mt] = __builtin_amdgcn_mfma_f32_16x16x32_bf16(af, pf, gacc[mt], 0, 0, 0);
        }
    }

    // h1 = relu(gacc + A[sn][u]) packed bf16 pairs in registers:
    // h1u[mt][rp] = bf16(u=mt*16+q*4+2rp) | bf16(u=...+2rp+1) << 16
    unsigned int h1u[8][2];
    {
        const float* Ab = A + ((size_t)bw * 20 + sIdx) * 128;
#pragma unroll
        for (int mt = 0; mt < 8; ++mt) {
            int u0 = mt * 16 + q * 4;
            float4 av = *(const float4*)&Ab[u0];
            unsigned int x0 = f2bf(fmaxf(gacc[mt][0] + av.x, 0.f));
            unsigned int x1 = f2bf(fmaxf(gacc[mt][1] + av.y, 0.f));
            unsigned int x2 = f2bf(fmaxf(gacc[mt][2] + av.z, 0.f));
            unsigned int x3 = f2bf(fmaxf(gacc[mt][3] + av.w, 0.f));
            h1u[mt][0] = x0 | (x1 << 16);
            h1u[mt][1] = x2 | (x3 << 16);
        }
    }

    // h2 GEMM: kt-outer; A-frag built by quad shuffles (m16 preserved).
    // target elem pair p (e=2p,2p+1): src lane = m16 + 16*((2q+(p>>1))&3),
    // src word = h1u[kt*2 + (q>>1)][p&1].
    floatx4 acc[8];
#pragma unroll
    for (int jt = 0; jt < 8; ++jt) acc[jt] = (floatx4){0.f, 0.f, 0.f, 0.f};

    const int sl0 = m16 + 16 * ((2 * q) & 3);
    const int sl1 = m16 + 16 * ((2 * q + 1) & 3);
    const bool hi = (q & 2);
#pragma unroll
    for (int kt = 0; kt < 4; ++kt) {
        int wa0 = __shfl((int)h1u[kt * 2 + 0][0], sl0);
        int wb0 = __shfl((int)h1u[kt * 2 + 1][0], sl0);
        int wa1 = __shfl((int)h1u[kt * 2 + 0][1], sl0);
        int wb1 = __shfl((int)h1u[kt * 2 + 1][1], sl0);
        int wa2 = __shfl((int)h1u[kt * 2 + 0][0], sl1);
        int wb2 = __shfl((int)h1u[kt * 2 + 1][0], sl1);
        int wa3 = __shfl((int)h1u[kt * 2 + 0][1], sl1);
        int wb3 = __shfl((int)h1u[kt * 2 + 1][1], sl1);
        int4 fr;
        fr.x = hi ? wb0 : wa0;
        fr.y = hi ? wb1 : wa1;
        fr.z = hi ? wb2 : wa2;
        fr.w = hi ? wb3 : wa3;
        bf16x8 af2 = *(bf16x8*)&fr;
        const int k0 = kt * 32 + q * 8;
#pragma unroll
        for (int jt = 0; jt < 8; ++jt) {
            bf16x8 bfr = *(const bf16x8*)&shW[(jt * 16 + m16) * 136 + k0];
            acc[jt] = __builtin_amdgcn_mfma_f32_16x16x32_bf16(af2, bfr, acc[jt], 0, 0, 0);
        }
    }

    // epilogue (verbatim k4): relu + W3 dot + quad reduce
    float b2v[8], w3v[8];
#pragma unroll
    for (int jt = 0; jt < 8; ++jt) {
        b2v[jt] = b2[jt * 16 + m16];
        w3v[jt] = W3[jt * 16 + m16];
    }
    const float b3v = b3[0];
#pragma unroll
    for (int reg = 0; reg < 4; ++reg) {
        float p = 0.f;
#pragma unroll
        for (int jt = 0; jt < 8; ++jt)
            p += fmaxf(acc[jt][reg] + b2v[jt], 0.f) * w3v[jt];
        p += __shfl_xor(p, 1);
        p += __shfl_xor(p, 2);
        p += __shfl_xor(p, 4);
        p += __shfl_xor(p, 8);
        if (m16 == 0)
            lg[(size_t)bw * 160 + wave * 16 + q * 4 + reg] = p + b3v;
    }
}

// ---------------------------------------------------------------------------
// K5: masked max over W, labels, scalar (verbatim).
// ---------------------------------------------------------------------------
__global__ __launch_bounds__(256) void k5_final(
    const float* __restrict__ lg,
    const float* __restrict__ mask,
    float* __restrict__ out)
{
    int idx = blockIdx.x * 256 + threadIdx.x;
    const int SN = S_ * N_;
    if (idx < B_ * SN) {
        int b = idx / SN, sn = idx % SN;
        float m = -INFINITY;
        for (int w = 0; w < W_; ++w) {
            float v = lg[((size_t)b * W_ + w) * SN + sn] + mask[((size_t)b * W_ + w) * SN + sn];
            m = fmaxf(m, v);
        }
        out[idx] = (m > 0.f) ? 1.f : 0.f;
        out[B_ * SN + 1 + idx] = m;
    }
    if (idx == 0) out[B_ * SN] = (float)SN;
}

// ---------------------------------------------------------------------------
extern "C" void kernel_launch(void* const* d_in, const int* in_sizes, int n_in,
                              void* d_out, int out_size, void* d_ws, size_t ws_size,
                              hipStream_t stream) {
    const float* slot_utt_h = (const float*)d_in[0];
    const float* slot_candidate_c = (const float*)d_in[1];
    const float* position_encoding = (const float*)d_in[3];
    const float* q_status = (const float*)d_in[4];
    const float* mask = (const float*)d_in[5];
    const float* weight = (const float*)d_in[6];
    const float* W1 = (const float*)d_in[7];
    const float* b1 = (const float*)d_in[8];
    const float* W2 = (const float*)d_in[9];
    const float* b2 = (const float*)d_in[10];
    const float* W3 = (const float*)d_in[11];
    const float* b3 = (const float*)d_in[12];
    float* out = (float*)d_out;

    float* f = (float*)d_ws;
    float*    lg        = f + 0;                      //   163,840 f
    float*    A         = f + 163840;                 // 2,621,440 f
    ushort_t* q_slot_bf = (ushort_t*)(f + 2785280);   // 2,621,440 sh
    ushort_t* co_bf     = (ushort_t*)(f + 4096000);   // 2,621,440 sh
    ushort_t* Gt_bf     = (ushort_t*)(f + 5406720);   // 1,048,576 sh
    ushort_t* qs1T_bf   = (ushort_t*)(f + 5931008);   // 1,048,576 sh
    ushort_t* w1topT    = (ushort_t*)(f + 6455296);   //    16,384 sh
    ushort_t* w2T       = (ushort_t*)(f + 6463488);   //    16,384 sh
    ushort_t* c_bf      = (ushort_t*)(f + 6471680);   //     4,096 sh

    k_pre<<<161, 256, 0, stream>>>(q_status, weight, W1, W2,
                                   slot_candidate_c,
                                   w1topT, w2T, c_bf, Gt_bf, qs1T_bf);
    kA<<<1024, 256, 0, stream>>>(slot_utt_h, c_bf, position_encoding, q_slot_bf);
    kB<<<640, 256, 0, stream>>>(q_slot_bf, Gt_bf, w1topT, b1, co_bf, A);
    kC<<<1024, 640, 0, stream>>>(co_bf, qs1T_bf, A, w2T, b2, W3, b3, lg);
    k5_final<<<(B_ * S_ * N_ + 255) / 256, 256, 0, stream>>>(lg, mask, out);
}

// Round 6
// 177.331 us; speedup vs baseline: 1.0591x; 1.0086x over previous
//
#include <hip/hip_runtime.h>
#include <math.h>

#define INF_ 100000.0f
constexpr int B_ = 64, W_ = 16, T_ = 64, U_ = 128, S_ = 20, N_ = 8;

typedef unsigned short ushort_t;
typedef __attribute__((ext_vector_type(8))) short bf16x8;
typedef __attribute__((ext_vector_type(4))) float floatx4;

static __device__ __forceinline__ unsigned short f2bf(float x) {
    unsigned int u = __float_as_uint(x);
    return (unsigned short)((u + 0x7fff + ((u >> 16) & 1)) >> 16);  // RNE
}
static __device__ __forceinline__ float bf2f(unsigned short s) {
    return __uint_as_float(((unsigned int)s) << 16);
}

// sh_hT XOR swizzle: permutes 8-ushort blocks of the t-dim by row bits.
// Write conflicts 16-way -> ~2-way; reads remain 16B-aligned b128.
#define HT_SWZ(u, t) ((u) * 72 + ((t) ^ ((((u) >> 3) & 7) << 3)))

// ---------------------------------------------------------------------------
// K_pre (verbatim, proven): input-only derived tensors.
// ---------------------------------------------------------------------------
__global__ __launch_bounds__(256) void k_pre(
    const float* __restrict__ q_status, const float* __restrict__ weight,
    const float* __restrict__ W1, const float* __restrict__ W2,
    const float* __restrict__ c,
    ushort_t* __restrict__ w1topT, ushort_t* __restrict__ w2T,
    ushort_t* __restrict__ c_bf,
    ushort_t* __restrict__ Gt_bf, ushort_t* __restrict__ qs1T_bf)
{
    __shared__ __align__(16) ushort_t sw[128 * 136];
    __shared__ __align__(16) ushort_t sq[128 * 136];
    const int tid = threadIdx.x, bx = blockIdx.x;

    if (bx < 64) {
        const int b = bx;
        const float* qb = q_status + (size_t)b * 16384;
        for (int i = tid * 4; i < 16384; i += 1024) {
            int r = i >> 7, v = i & 127;
            float4 wv = *(const float4*)&weight[i];
            *(ushort4*)&sw[r * 136 + v] =
                (ushort4){f2bf(wv.x), f2bf(wv.y), f2bf(wv.z), f2bf(wv.w)};
            float4 qv = *(const float4*)&qb[i];
            *(ushort4*)&sq[r * 136 + v] =
                (ushort4){f2bf(qv.x), f2bf(qv.y), f2bf(qv.z), f2bf(qv.w)};
        }
        __syncthreads();
        const int wave = tid >> 6, lane = tid & 63, m16 = lane & 15, q = lane >> 4;
        ushort_t* Gb = Gt_bf + (size_t)b * 16384;
#pragma unroll
        for (int ci = 0; ci < 16; ++ci) {
            int tile = wave * 16 + ci;
            int mt = tile >> 3, jt = tile & 7;
            floatx4 acc = {0.f, 0.f, 0.f, 0.f};
#pragma unroll
            for (int kt = 0; kt < 4; ++kt) {
                bf16x8 a = *(const bf16x8*)&sq[(mt * 16 + m16) * 136 + kt * 32 + q * 8];
                bf16x8 w = *(const bf16x8*)&sw[(jt * 16 + m16) * 136 + kt * 32 + q * 8];
                acc = __builtin_amdgcn_mfma_f32_16x16x32_bf16(a, w, acc, 0, 0, 0);
            }
#pragma unroll
            for (int reg = 0; reg < 4; ++reg)
                Gb[(mt * 16 + q * 4 + reg) * 128 + jt * 16 + m16] = f2bf(acc[reg]);
        }
        return;
    }
    if (bx < 128) {
        const int b = bx - 64;
        const float* qb = q_status + (size_t)b * 16384;
        for (int i = tid * 4; i < 16384; i += 1024) {
            int r = i >> 7, v = i & 127;
            float4 qv = *(const float4*)&qb[i];
            *(ushort4*)&sq[r * 136 + v] =
                (ushort4){f2bf(qv.x), f2bf(qv.y), f2bf(qv.z), f2bf(qv.w)};
            int v2 = i >> 7, j = i & 127;
            float4 wv = *(const float4*)&W1[(128 + v2) * 128 + j];
            sw[(j + 0) * 136 + v2] = f2bf(wv.x);
            sw[(j + 1) * 136 + v2] = f2bf(wv.y);
            sw[(j + 2) * 136 + v2] = f2bf(wv.z);
            sw[(j + 3) * 136 + v2] = f2bf(wv.w);
        }
        __syncthreads();
        const int wave = tid >> 6, lane = tid & 63, m16 = lane & 15, q = lane >> 4;
        ushort_t* Qb = qs1T_bf + (size_t)b * 16384;
#pragma unroll
        for (int ci = 0; ci < 16; ++ci) {
            int tile = wave * 16 + ci;
            int mt = tile >> 3, jt = tile & 7;
            floatx4 acc = {0.f, 0.f, 0.f, 0.f};
#pragma unroll
            for (int kt = 0; kt < 4; ++kt) {
                bf16x8 a = *(const bf16x8*)&sq[(mt * 16 + m16) * 136 + kt * 32 + q * 8];
                bf16x8 w = *(const bf16x8*)&sw[(jt * 16 + m16) * 136 + kt * 32 + q * 8];
                acc = __builtin_amdgcn_mfma_f32_16x16x32_bf16(a, w, acc, 0, 0, 0);
            }
            ushort4 o = {f2bf(acc[0]), f2bf(acc[1]), f2bf(acc[2]), f2bf(acc[3])};
            *(ushort4*)&Qb[(jt * 16 + m16) * 128 + mt * 16 + q * 4] = o;
        }
        return;
    }
    if (bx < 144) {
        int g = (bx - 128) * 1024 + tid * 4;
        int j = g >> 7, k = g & 127;
        *(ushort4*)&w1topT[g] =
            (ushort4){f2bf(W1[k * 128 + j]), f2bf(W1[(k + 1) * 128 + j]),
                      f2bf(W1[(k + 2) * 128 + j]), f2bf(W1[(k + 3) * 128 + j])};
        return;
    }
    if (bx < 160) {
        int g = (bx - 144) * 1024 + tid * 4;
        int j = g >> 7, k = g & 127;
        *(ushort4*)&w2T[g] =
            (ushort4){f2bf(W2[k * 128 + j]), f2bf(W2[(k + 1) * 128 + j]),
                      f2bf(W2[(k + 2) * 128 + j]), f2bf(W2[(k + 3) * 128 + j])};
        return;
    }
    for (int i = tid * 4; i < 4096; i += 1024) {
        int s = i >> 7;
        ushort4 o = {0, 0, 0, 0};
        if (s < 20) {
            float4 v = *(const float4*)&c[i];
            o = (ushort4){f2bf(v.x), f2bf(v.y), f2bf(v.z), f2bf(v.w)};
        }
        *(ushort4*)&c_bf[i] = o;
    }
}

// ---------------------------------------------------------------------------
// kA: attention per bw. 256 thr, LDS 31744 B -> 5 blk/CU.
// sh_hT now XOR-swizzled (HT_SWZ) on both write and read: 16-way write
// conflict -> ~2-way.  Everything else verbatim R5.
// ---------------------------------------------------------------------------
__global__ __launch_bounds__(256) void kA(
    const float* __restrict__ h,        // [B*W][64][128] f32
    const ushort_t* __restrict__ c_bf,  // [32][128], rows>=20 zero
    const float* __restrict__ pos,      // [B*W][20][128] f32
    ushort_t* __restrict__ q_slot_bf)   // [20480][128]
{
    __shared__ __align__(16) ushort_t sh_hT[128 * 72];  // [u][t swz] 18432 B
    __shared__ __align__(16) float    sh_sc[32 * 68];   //  8704 B
    __shared__ __align__(16) ushort_t sh_P[32 * 72];    //  4608 B

    const int bw = blockIdx.x, tid = threadIdx.x;
    const int wave = tid >> 6, lane = tid & 63, m16 = lane & 15, q = lane >> 4;
    const float* hb = h + (size_t)bw * 8192;

    // P1: stage hT (swizzled scalar writes) + zero P
    for (int i = tid * 4; i < 8192; i += 1024) {
        int t = i >> 7, u = i & 127;
        float4 v = *(const float4*)&hb[i];
        sh_hT[HT_SWZ(u + 0, t)] = f2bf(v.x);
        sh_hT[HT_SWZ(u + 1, t)] = f2bf(v.y);
        sh_hT[HT_SWZ(u + 2, t)] = f2bf(v.z);
        sh_hT[HT_SWZ(u + 3, t)] = f2bf(v.w);
    }
    for (int i = tid; i < 2304; i += 256) sh_P[i] = 0;

    // P2: sc = c @ h^T, A/B from global (no LDS dependence)
#pragma unroll
    for (int ci = 0; ci < 2; ++ci) {
        int cmb = wave * 2 + ci;                 // 0..7
        int mt = cmb >> 2, jt = cmb & 3;
        floatx4 acc = {0.f, 0.f, 0.f, 0.f};
#pragma unroll
        for (int kt = 0; kt < 4; ++kt) {
            bf16x8 a = *(const bf16x8*)&c_bf[(mt * 16 + m16) * 128 + kt * 32 + q * 8];
            const float* hp = &hb[(jt * 16 + m16) * 128 + kt * 32 + q * 8];
            float4 b0 = *(const float4*)&hp[0];
            float4 b1v = *(const float4*)&hp[4];
            bf16x8 bb;
            bb[0] = (short)f2bf(b0.x); bb[1] = (short)f2bf(b0.y);
            bb[2] = (short)f2bf(b0.z); bb[3] = (short)f2bf(b0.w);
            bb[4] = (short)f2bf(b1v.x); bb[5] = (short)f2bf(b1v.y);
            bb[6] = (short)f2bf(b1v.z); bb[7] = (short)f2bf(b1v.w);
            acc = __builtin_amdgcn_mfma_f32_16x16x32_bf16(a, bb, acc, 0, 0, 0);
        }
#pragma unroll
        for (int reg = 0; reg < 4; ++reg)
            sh_sc[(mt * 16 + q * 4 + reg) * 68 + jt * 16 + m16] = acc[reg];
    }
    __syncthreads();

    // P3: softmax over t
    for (int s = wave; s < 20; s += 4) {
        float v = sh_sc[s * 68 + lane];
        if (v == 0.0f) v = -INF_;
        float m = v;
        for (int d = 32; d; d >>= 1) m = fmaxf(m, __shfl_xor(m, d));
        float e = expf(v - m);
        float sum = e;
        for (int d = 32; d; d >>= 1) sum += __shfl_xor(sum, d);
        sh_P[s * 72 + lane] = f2bf(e / sum);
    }
    __syncthreads();

    // P4: q_slot = P@h + pos -> global bf16 (sh_hT reads via HT_SWZ)
    const size_t obase = (size_t)bw * 2560;
#pragma unroll
    for (int ci = 0; ci < 4; ++ci) {
        int cmb = wave * 4 + ci;                 // 0..15
        int mt = cmb >> 3, jt = cmb & 7;
        floatx4 acc = {0.f, 0.f, 0.f, 0.f};
#pragma unroll
        for (int kt = 0; kt < 2; ++kt) {
            bf16x8 a = *(const bf16x8*)&sh_P[(mt * 16 + m16) * 72 + kt * 32 + q * 8];
            bf16x8 b = *(const bf16x8*)&sh_hT[HT_SWZ(jt * 16 + m16, kt * 32 + q * 8)];
            acc = __builtin_amdgcn_mfma_f32_16x16x32_bf16(a, b, acc, 0, 0, 0);
        }
        int u = jt * 16 + m16;
#pragma unroll
        for (int reg = 0; reg < 4; ++reg) {
            int row = mt * 16 + q * 4 + reg;
            if (row < 20)
                q_slot_bf[obase + row * 128 + u] =
                    f2bf(acc[reg] + pos[obase + row * 128 + u]);
        }
    }
}

// ---------------------------------------------------------------------------
// kB: dense batched GEMMs (verbatim R5).  256 thr, 34816 B -> 4 blk/CU.
// ---------------------------------------------------------------------------
__global__ __launch_bounds__(256) void kB(
    const ushort_t* __restrict__ q_slot_bf,  // [20480][128]
    const ushort_t* __restrict__ Gt_bf,      // [B][128][128]
    const ushort_t* __restrict__ w1topT,     // [128][128]
    const float* __restrict__ b1,
    ushort_t* __restrict__ co_bf,            // [B][320][128]
    float* __restrict__ A)                   // [20480][128]
{
    __shared__ __align__(16) ushort_t shB[128 * 136];
    const int tid = threadIdx.x, bx = blockIdx.x;
    const int wave = tid >> 6, lane = tid & 63, m16 = lane & 15, q = lane >> 4;

    if (bx < 320) {
        const int b = bx / 5, rt = bx - b * 5;
        for (int i = tid * 4; i < 16384; i += 1024)
            *(ushort4*)&shB[(i >> 7) * 136 + (i & 127)] =
                *(const ushort4*)&Gt_bf[(size_t)b * 16384 + i];
        __syncthreads();

        const size_t rbase = (size_t)b * 320 + rt * 64 + wave * 16;
        floatx4 acc[8];
#pragma unroll
        for (int jt = 0; jt < 8; ++jt) acc[jt] = (floatx4){0.f, 0.f, 0.f, 0.f};
#pragma unroll
        for (int kt = 0; kt < 4; ++kt) {
            bf16x8 a = *(const bf16x8*)&q_slot_bf[(rbase + m16) * 128 + kt * 32 + q * 8];
#pragma unroll
            for (int jt = 0; jt < 8; ++jt) {
                bf16x8 g = *(const bf16x8*)&shB[(jt * 16 + m16) * 136 + kt * 32 + q * 8];
                acc[jt] = __builtin_amdgcn_mfma_f32_16x16x32_bf16(a, g, acc[jt], 0, 0, 0);
            }
        }
#pragma unroll
        for (int jt = 0; jt < 8; ++jt)
#pragma unroll
            for (int reg = 0; reg < 4; ++reg)
                co_bf[(rbase + q * 4 + reg) * 128 + jt * 16 + m16] = f2bf(acc[jt][reg]);
    } else {
        const int blk = bx - 320;                // 0..319, 64 rows each
        for (int i = tid * 4; i < 16384; i += 1024)
            *(ushort4*)&shB[(i >> 7) * 136 + (i & 127)] =
                *(const ushort4*)&w1topT[i];
        __syncthreads();

        const size_t rbase = (size_t)blk * 64 + wave * 16;
        floatx4 acc[8];
#pragma unroll
        for (int jt = 0; jt < 8; ++jt) acc[jt] = (floatx4){0.f, 0.f, 0.f, 0.f};
#pragma unroll
        for (int kt = 0; kt < 4; ++kt) {
            bf16x8 a = *(const bf16x8*)&q_slot_bf[(rbase + m16) * 128 + kt * 32 + q * 8];
#pragma unroll
            for (int jt = 0; jt < 8; ++jt) {
                bf16x8 g = *(const bf16x8*)&shB[(jt * 16 + m16) * 136 + kt * 32 + q * 8];
                acc[jt] = __builtin_amdgcn_mfma_f32_16x16x32_bf16(a, g, acc[jt], 0, 0, 0);
            }
        }
#pragma unroll
        for (int jt = 0; jt < 8; ++jt) {
            int col = jt * 16 + m16;
            float bv = b1[col];
#pragma unroll
            for (int reg = 0; reg < 4; ++reg)
                A[(rbase + q * 4 + reg) * 128 + col] = acc[jt][reg] + bv;
        }
    }
}

// ---------------------------------------------------------------------------
// kC: softmax(co) -> h1^T -> h1(reg) -> quad-shuffle -> h2 -> logits.
// LDS time-multiplexed: one 34816 B buffer holds qs1T (phase A) then w2T
// (phase B).  40096 B total -> 3 blk/CU (needs VGPR<=64: bounds (640,8)).
// h1 crosses the restage in registers (h1u).  3 barriers.
// ---------------------------------------------------------------------------
__global__ __launch_bounds__(640, 8) void kC(
    const ushort_t* __restrict__ co_bf,    // [B][320][128]
    const ushort_t* __restrict__ qs1T_bf,  // [B][128 u][128 xn]
    const float* __restrict__ A,           // [20480][128]
    const ushort_t* __restrict__ w2T,      // [128 j][128 k]
    const float* __restrict__ b2,
    const float* __restrict__ W3,
    const float* __restrict__ b3,
    float* __restrict__ lg)                // [B*W][160]
{
    __shared__ __align__(16) ushort_t shB[128 * 136];  // qs1T then w2T
    __shared__ __align__(16) ushort_t shP[20 * 132];   // p2  5280 B

    const int bw = blockIdx.x, b = bw >> 4, tid = threadIdx.x;
    const int wave = tid >> 6, lane = tid & 63, m16 = lane & 15, q = lane >> 4;

    // stage qs1T[b]
    for (int i = tid * 4; i < 16384; i += 2560) {
        int r = i >> 7, k = i & 127;
        *(ushort4*)&shB[r * 136 + k] = *(const ushort4*)&qs1T_bf[(size_t)b * 16384 + i];
    }

    // softmax over x (co from global; 640 thr cover 160 sn x 4 xi)
    {
        int sn = tid >> 2, xi = tid & 3;
        int s = sn >> 3, n2 = sn & 7;
        const ushort_t* crow = co_bf + ((size_t)bw * 20 + s) * 128;
        float v[4];
        float m = -INFINITY;
#pragma unroll
        for (int j = 0; j < 4; ++j) {
            float t = bf2f(crow[(xi + 4 * j) * 8 + n2]);
            if (t == 0.0f) t = -INF_;
            v[j] = t;
            m = fmaxf(m, t);
        }
        m = fmaxf(m, __shfl_xor(m, 1));
        m = fmaxf(m, __shfl_xor(m, 2));
        float sum = 0.f;
#pragma unroll
        for (int j = 0; j < 4; ++j) { v[j] = expf(v[j] - m); sum += v[j]; }
        sum += __shfl_xor(sum, 1);
        sum += __shfl_xor(sum, 2);
        float r = 1.0f / sum;
#pragma unroll
        for (int j = 0; j < 4; ++j)
            shP[s * 132 + (xi + 4 * j) * 8 + n2] = f2bf(v[j] * r);
    }
    __syncthreads();

    const int n = m16 & 7;
    const int sIdx = wave * 2 + (m16 >> 3);

    // h1^T MFMA: A-frags from LDS shB(qs1T), sparse-p2 B-frags
    floatx4 gacc[8];
#pragma unroll
    for (int mt = 0; mt < 8; ++mt) gacc[mt] = (floatx4){0.f, 0.f, 0.f, 0.f};
#pragma unroll
    for (int kt = 0; kt < 4; ++kt) {
        short pv = (short)shP[sIdx * 132 + kt * 32 + q * 8 + n];
        bf16x8 pf = {0, 0, 0, 0, 0, 0, 0, 0};
        pf[0] = (n == 0) ? pv : (short)0;
        pf[1] = (n == 1) ? pv : (short)0;
        pf[2] = (n == 2) ? pv : (short)0;
        pf[3] = (n == 3) ? pv : (short)0;
        pf[4] = (n == 4) ? pv : (short)0;
        pf[5] = (n == 5) ? pv : (short)0;
        pf[6] = (n == 6) ? pv : (short)0;
        pf[7] = (n == 7) ? pv : (short)0;
#pragma unroll
        for (int mt = 0; mt < 8; ++mt) {
            bf16x8 af = *(const bf16x8*)&shB[(mt * 16 + m16) * 136 + kt * 32 + q * 8];
            gacc[mt] = __builtin_amdgcn_mfma_f32_16x16x32_bf16(af, pf, gacc[mt], 0, 0, 0);
        }
    }

    // h1 = relu(gacc + A[sn][u]) packed bf16 pairs in registers
    unsigned int h1u[8][2];
    {
        const float* Ab = A + ((size_t)bw * 20 + sIdx) * 128;
#pragma unroll
        for (int mt = 0; mt < 8; ++mt) {
            int u0 = mt * 16 + q * 4;
            float4 av = *(const float4*)&Ab[u0];
            unsigned int x0 = f2bf(fmaxf(gacc[mt][0] + av.x, 0.f));
            unsigned int x1 = f2bf(fmaxf(gacc[mt][1] + av.y, 0.f));
            unsigned int x2 = f2bf(fmaxf(gacc[mt][2] + av.z, 0.f));
            unsigned int x3 = f2bf(fmaxf(gacc[mt][3] + av.w, 0.f));
            h1u[mt][0] = x0 | (x1 << 16);
            h1u[mt][1] = x2 | (x3 << 16);
        }
    }
    __syncthreads();   // shB(qs1T) reads done

    // restage shB = w2T
    for (int i = tid * 4; i < 16384; i += 2560) {
        int r = i >> 7, k = i & 127;
        *(ushort4*)&shB[r * 136 + k] = *(const ushort4*)&w2T[i];
    }
    __syncthreads();

    // h2 GEMM: kt-outer; A-frag built by quad shuffles (m16 preserved).
    floatx4 acc[8];
#pragma unroll
    for (int jt = 0; jt < 8; ++jt) acc[jt] = (floatx4){0.f, 0.f, 0.f, 0.f};

    const int sl0 = m16 + 16 * ((2 * q) & 3);
    const int sl1 = m16 + 16 * ((2 * q + 1) & 3);
    const bool hi = (q & 2);
#pragma unroll
    for (int kt = 0; kt < 4; ++kt) {
        int wa0 = __shfl((int)h1u[kt * 2 + 0][0], sl0);
        int wb0 = __shfl((int)h1u[kt * 2 + 1][0], sl0);
        int wa1 = __shfl((int)h1u[kt * 2 + 0][1], sl0);
        int wb1 = __shfl((int)h1u[kt * 2 + 1][1], sl0);
        int wa2 = __shfl((int)h1u[kt * 2 + 0][0], sl1);
        int wb2 = __shfl((int)h1u[kt * 2 + 1][0], sl1);
        int wa3 = __shfl((int)h1u[kt * 2 + 0][1], sl1);
        int wb3 = __shfl((int)h1u[kt * 2 + 1][1], sl1);
        int4 fr;
        fr.x = hi ? wb0 : wa0;
        fr.y = hi ? wb1 : wa1;
        fr.z = hi ? wb2 : wa2;
        fr.w = hi ? wb3 : wa3;
        bf16x8 af2 = *(bf16x8*)&fr;
        const int k0 = kt * 32 + q * 8;
#pragma unroll
        for (int jt = 0; jt < 8; ++jt) {
            bf16x8 bfr = *(const bf16x8*)&shB[(jt * 16 + m16) * 136 + k0];
            acc[jt] = __builtin_amdgcn_mfma_f32_16x16x32_bf16(af2, bfr, acc[jt], 0, 0, 0);
        }
    }

    // epilogue: relu + W3 dot + quad reduce
    float b2v[8], w3v[8];
#pragma unroll
    for (int jt = 0; jt < 8; ++jt) {
        b2v[jt] = b2[jt * 16 + m16];
        w3v[jt] = W3[jt * 16 + m16];
    }
    const float b3v = b3[0];
#pragma unroll
    for (int reg = 0; reg < 4; ++reg) {
        float p = 0.f;
#pragma unroll
        for (int jt = 0; jt < 8; ++jt)
            p += fmaxf(acc[jt][reg] + b2v[jt], 0.f) * w3v[jt];
        p += __shfl_xor(p, 1);
        p += __shfl_xor(p, 2);
        p += __shfl_xor(p, 4);
        p += __shfl_xor(p, 8);
        if (m16 == 0)
            lg[(size_t)bw * 160 + wave * 16 + q * 4 + reg] = p + b3v;
    }
}

// ---------------------------------------------------------------------------
// K5: masked max over W, labels, scalar (verbatim).
// ---------------------------------------------------------------------------
__global__ __launch_bounds__(256) void k5_final(
    const float* __restrict__ lg,
    const float* __restrict__ mask,
    float* __restrict__ out)
{
    int idx = blockIdx.x * 256 + threadIdx.x;
    const int SN = S_ * N_;
    if (idx < B_ * SN) {
        int b = idx / SN, sn = idx % SN;
        float m = -INFINITY;
        for (int w = 0; w < W_; ++w) {
            float v = lg[((size_t)b * W_ + w) * SN + sn] + mask[((size_t)b * W_ + w) * SN + sn];
            m = fmaxf(m, v);
        }
        out[idx] = (m > 0.f) ? 1.f : 0.f;
        out[B_ * SN + 1 + idx] = m;
    }
    if (idx == 0) out[B_ * SN] = (float)SN;
}

// ---------------------------------------------------------------------------
extern "C" void kernel_launch(void* const* d_in, const int* in_sizes, int n_in,
                              void* d_out, int out_size, void* d_ws, size_t ws_size,
                              hipStream_t stream) {
    const float* slot_utt_h = (const float*)d_in[0];
    const float* slot_candidate_c = (const float*)d_in[1];
    const float* position_encoding = (const float*)d_in[3];
    const float* q_status = (const float*)d_in[4];
    const float* mask = (const float*)d_in[5];
    const float* weight = (const float*)d_in[6];
    const float* W1 = (const float*)d_in[7];
    const float* b1 = (const float*)d_in[8];
    const float* W2 = (const float*)d_in[9];
    const float* b2 = (const float*)d_in[10];
    const float* W3 = (const float*)d_in[11];
    const float* b3 = (const float*)d_in[12];
    float* out = (float*)d_out;

    float* f = (float*)d_ws;
    float*    lg        = f + 0;                      //   163,840 f
    float*    A         = f + 163840;                 // 2,621,440 f
    ushort_t* q_slot_bf = (ushort_t*)(f + 2785280);   // 2,621,440 sh
    ushort_t* co_bf     = (ushort_t*)(f + 4096000);   // 2,621,440 sh
    ushort_t* Gt_bf     = (ushort_t*)(f + 5406720);   // 1,048,576 sh
    ushort_t* qs1T_bf   = (ushort_t*)(f + 5931008);   // 1,048,576 sh
    ushort_t* w1topT    = (ushort_t*)(f + 6455296);   //    16,384 sh
    ushort_t* w2T       = (ushort_t*)(f + 6463488);   //    16,384 sh
    ushort_t* c_bf      = (ushort_t*)(f + 6471680);   //     4,096 sh

    k_pre<<<161, 256, 0, stream>>>(q_status, weight, W1, W2,
                                   slot_candidate_c,
                                   w1topT, w2T, c_bf, Gt_bf, qs1T_bf);
    kA<<<1024, 256, 0, stream>>>(slot_utt_h, c_bf, position_encoding, q_slot_bf);
    kB<<<640, 256, 0, stream>>>(q_slot_bf, Gt_bf, w1topT, b1, co_bf, A);
    kC<<<1024, 640, 0, stream>>>(co_bf, qs1T_bf, A, w2T, b2, W3, b3, lg);
    k5_final<<<(B_ * S_ * N_ + 255) / 256, 256, 0, stream>>>(lg, mask, out);
}